// Round 5
// baseline (233.853 us; speedup 1.0000x reference)
//
#include <hip/hip_runtime.h>
#include <math.h>

#define N_NODES 50000
#define N_EDGES 500000
#define DIM     128
#define NGRAPH  50
#define NPGC    1000
#define KSEL    500
#define SORT_N  1024
#define NBE     489    // ceil(N_EDGES / 1024)
#define GEMM_BLKS 782  // ceil(N_NODES / 64)
#define EDGE_BLKS 1954 // ceil(N_EDGES / 256)
#define NDINV     196  // ceil(N_NODES / 256)
#define GATH_BLKS 6250
#define DEGB    64     // private-histogram deg blocks (workgroup-scope atomics)
#define NCHUNK  1954   // ceil(N_EDGES / 256) edge chunks, round-robin over DEGB blocks

// =============== K1b: deg count (private hist, wg-scope atomics) ===============
// Block b owns degpriv[b][N]; chunks c ≡ b (mod 64). eslot[e] = within-(block,node) slot.
// Split from the gemm kernel so rocprof reports deg and gemm durations separately.

__global__ __launch_bounds__(256) void k1b_deg(const int* __restrict__ dst,
                                               int* __restrict__ degpriv,
                                               int* __restrict__ eslot) {
    int t = threadIdx.x;
    int b = blockIdx.x;
    int* priv = degpriv + b * N_NODES;
    for (int c = b; c < NCHUNK; c += 2 * DEGB) {
        int e1 = (c << 8) + t;
        int cB = c + DEGB;
        int e2 = (cB << 8) + t;
        int d1 = (e1 < N_EDGES) ? dst[e1] : -1;
        int d2 = (cB < NCHUNK && e2 < N_EDGES) ? dst[e2] : -1;
        if (d1 >= 0)
            eslot[e1] = __hip_atomic_fetch_add(&priv[d1], 1, __ATOMIC_RELAXED,
                                               __HIP_MEMORY_SCOPE_WORKGROUP);
        if (d2 >= 0)
            eslot[e2] = __hip_atomic_fetch_add(&priv[d2], 1, __ATOMIC_RELAXED,
                                               __HIP_MEMORY_SCOPE_WORKGROUP);
    }
}

// =============== K1a: gemm (xw = x @ W_fu) + fused f64 dots (x.W_s, x.W_f) ===============
// 64 nodes x 128 ch per block, ~49KB LDS. The x-tile staged for the gemm is reused
// for the score dot products (4 threads/node x 16 k per half, f64 accumulate),
// eliminating k2's 12500-block dots pass and its 25.6MB x re-read.

__global__ __launch_bounds__(256) void k1a_gemm_dots(const float* __restrict__ x,
                                                     const float* __restrict__ W,
                                                     float* __restrict__ xw,
                                                     const float* __restrict__ Ws,
                                                     const float* __restrict__ Wf,
                                                     const float* __restrict__ bf,
                                                     double* __restrict__ pack,
                                                     double* __restrict__ sf) {
    __shared__ float lds[12544];            // Wt 8192 | Xt 4096 | Wsl 128 | Wfl 128
    int t = threadIdx.x;
    float* Wt  = lds;                       // [k][ch], 64*128
    float* Xt  = lds + 8192;                // [node][k-half], swizzled, 64*64
    float* Wsl = lds + 12288;               // Ws staged (128)
    float* Wfl = lds + 12416;               // Wf staged (128)
    int cg = t & 15;
    int ng = t >> 4;
    int node_base = blockIdx.x * 64;

    if (t < 128) Wsl[t] = Ws[t];
    else         Wfl[t - 128] = Wf[t - 128];

    // fused-dot state: 4 threads per node, each owns 16 k's per half
    int dn  = t >> 2;                       // node row 0..63
    int dk4 = (t & 3) << 4;                 // k offset within half: 0/16/32/48
    double ps = 0.0, pf = 0.0;

    float4 acc[4][2];
    #pragma unroll
    for (int nn = 0; nn < 4; nn++) {
        acc[nn][0] = make_float4(0.f, 0.f, 0.f, 0.f);
        acc[nn][1] = make_float4(0.f, 0.f, 0.f, 0.f);
    }
    for (int half = 0; half < 2; half++) {
        const float4* Wg = (const float4*)(W + half * 64 * DIM);
        float4* Wl = (float4*)Wt;
        #pragma unroll
        for (int i = 0; i < 8; i++) {
            int f = t + i * 256;
            Wl[f] = Wg[f];
        }
        #pragma unroll
        for (int i = 0; i < 4; i++) {
            int f = t + i * 256;            // 1024 float4 = 64 rows x 16
            int row = f >> 4, col = f & 15;
            int node = node_base + row;
            float4 v = make_float4(0.f, 0.f, 0.f, 0.f);
            if (node < N_NODES) v = *(const float4*)&x[(size_t)node * DIM + half * 64 + col * 4];
            *(float4*)&Xt[(row << 6) + ((col ^ (row & 15)) << 2)] = v;
        }
        __syncthreads();
        #pragma unroll 2
        for (int kc = 0; kc < 16; kc++) {
            int k = kc << 2;
            float4 wa[4], wb[4];
            #pragma unroll
            for (int kk = 0; kk < 4; kk++) {
                wa[kk] = *(const float4*)&Wt[(k + kk) * DIM + (cg << 2)];
                wb[kk] = *(const float4*)&Wt[(k + kk) * DIM + (cg << 2) + 64];
            }
            int csw = (kc ^ ng) << 2;
            #pragma unroll
            for (int nn = 0; nn < 4; nn++) {
                float4 xv = *(const float4*)&Xt[((ng + (nn << 4)) << 6) + csw];
                acc[nn][0].x += xv.x * wa[0].x + xv.y * wa[1].x + xv.z * wa[2].x + xv.w * wa[3].x;
                acc[nn][0].y += xv.x * wa[0].y + xv.y * wa[1].y + xv.z * wa[2].y + xv.w * wa[3].y;
                acc[nn][0].z += xv.x * wa[0].z + xv.y * wa[1].z + xv.z * wa[2].z + xv.w * wa[3].z;
                acc[nn][0].w += xv.x * wa[0].w + xv.y * wa[1].w + xv.z * wa[2].w + xv.w * wa[3].w;
                acc[nn][1].x += xv.x * wb[0].x + xv.y * wb[1].x + xv.z * wb[2].x + xv.w * wb[3].x;
                acc[nn][1].y += xv.x * wb[0].y + xv.y * wb[1].y + xv.z * wb[2].y + xv.w * wb[3].y;
                acc[nn][1].z += xv.x * wb[0].z + xv.y * wb[1].z + xv.z * wb[2].z + xv.w * wb[3].z;
                acc[nn][1].w += xv.x * wb[0].w + xv.y * wb[1].w + xv.z * wb[2].w + xv.w * wb[3].w;
            }
        }
        // fused dots for this half: read own node's staged x from Xt (swizzled)
        #pragma unroll 4
        for (int j = 0; j < 16; j++) {
            int k = dk4 + j;                // 0..63 within half
            int col = k >> 2, sub = k & 3;
            double xd = (double)Xt[(dn << 6) + ((col ^ (dn & 15)) << 2) + sub];
            ps += xd * (double)Wsl[half * 64 + k];
            pf += xd * (double)Wfl[half * 64 + k];
        }
        __syncthreads();
    }
    #pragma unroll
    for (int nn = 0; nn < 4; nn++) {
        int node = node_base + ng + (nn << 4);
        if (node < N_NODES) {
            *(float4*)&xw[(size_t)node * DIM + (cg << 2)]      = acc[nn][0];
            *(float4*)&xw[(size_t)node * DIM + (cg << 2) + 64] = acc[nn][1];
        }
    }
    // reduce dots across the 4 lanes of each node group, write pack/sf
    ps += __shfl_down(ps, 2, 64); ps += __shfl_down(ps, 1, 64);
    pf += __shfl_down(pf, 2, 64); pf += __shfl_down(pf, 1, 64);
    if ((t & 3) == 0) {
        int node = node_base + dn;
        if (node < N_NODES) {
            pack[2 * node + 1] = ps;        // xw_s
            sf[node] = pf + (double)bf[0];
        }
    }
}

// =============== K2: merge(deg, blockoff in-place) + dinv + rowoff scan ===============
// thread=node: deg=sum over 64 priv, priv->excl prefix (in place), dinv/pack;
// per-256-node rowoff scan -> bsums256[196].

__global__ __launch_bounds__(256) void k2_merge(int* __restrict__ degpriv,
                                                int* __restrict__ deg,
                                                int* __restrict__ rowoff,
                                                int* __restrict__ bsums256,
                                                double* __restrict__ pack,
                                                float* __restrict__ dinvf) {
    int t = threadIdx.x;
    int lane = t & 63, wid = t >> 6;
    int i = blockIdx.x * 256 + t;
    int o = 0;
    if (i < N_NODES) {
        #pragma unroll 8
        for (int b = 0; b < DEGB; b++) {
            int* p = &degpriv[b * N_NODES + i];
            int c = *p;
            *p = o;                              // exclusive prefix across blocks, in place
            o += c;
        }
        deg[i] = o;                              // total in-degree
        double di = 1.0 / sqrt((double)(o + 1));
        pack[2 * i] = di;
        dinvf[i] = (float)di;
    }
    __shared__ int ws4[4];
    int incl = o;
    #pragma unroll
    for (int off = 1; off < 64; off <<= 1) {
        int u = __shfl_up(incl, off, 64);
        if (lane >= off) incl += u;
    }
    if (lane == 63) ws4[wid] = incl;
    __syncthreads();
    int woff = 0;
    #pragma unroll
    for (int w = 0; w < 4; w++) if (w < wid) woff += ws4[w];
    if (i < N_NODES) rowoff[i] = incl - o + woff;
    if (t == 255) bsums256[blockIdx.x] = woff + incl;
}

// =============== K3: CSR fill, atomic-free ===============
// pos = rowoff[d] + bsN[d>>8] + degpriv[owner(e)][d] + eslot[e]; owner = (e>>8)&63.

__global__ __launch_bounds__(256) void k3_csr(const int* __restrict__ src,
                                              const int* __restrict__ dst,
                                              const int* __restrict__ rowoff,
                                              const int* __restrict__ bsums256,
                                              const int* __restrict__ degpriv,
                                              const int* __restrict__ eslot,
                                              int* __restrict__ csr) {
    __shared__ int bsN[256];
    int t = threadIdx.x;
    if (t < 64) {                               // one wave: scan 196 block sums, 4 chunks
        int carry = 0;
        #pragma unroll
        for (int ch = 0; ch < 4; ch++) {
            int i = ch * 64 + t;
            int v = (i < NDINV) ? bsums256[i] : 0;
            int incl = v;
            #pragma unroll
            for (int off = 1; off < 64; off <<= 1) {
                int u = __shfl_up(incl, off, 64);
                if (t >= off) incl += u;
            }
            bsN[i] = incl - v + carry;
            carry += __shfl(incl, 63, 64);
        }
    }
    __syncthreads();
    int e = blockIdx.x * 256 + t;
    if (e >= N_EDGES) return;
    int d = dst[e];
    int owner = (e >> 8) & (DEGB - 1);
    int pos = rowoff[d] + bsN[d >> 8] + degpriv[owner * N_NODES + d] + eslot[e];
    csr[pos] = src[e];
}

// =============== K3b: structure score via CSR gather (no atomics, f64) ===============

__global__ __launch_bounds__(256) void k3b_score(const int* __restrict__ csr,
                                                 const int* __restrict__ rowoff,
                                                 const int* __restrict__ bsums256,
                                                 const int* __restrict__ deg,
                                                 const double* __restrict__ pack,
                                                 double* __restrict__ score_sd) {
    __shared__ int bsN[256];
    int t = threadIdx.x;
    if (t < 64) {
        int carry = 0;
        #pragma unroll
        for (int ch = 0; ch < 4; ch++) {
            int i = ch * 64 + t;
            int v = (i < NDINV) ? bsums256[i] : 0;
            int incl = v;
            #pragma unroll
            for (int off = 1; off < 64; off <<= 1) {
                int u = __shfl_up(incl, off, 64);
                if (t >= off) incl += u;
            }
            bsN[i] = incl - v + carry;
            carry += __shfl(incl, 63, 64);
        }
    }
    __syncthreads();
    int node = blockIdx.x * 256 + t;
    if (node >= N_NODES) return;
    int base = rowoff[node] + bsN[node >> 8];
    int cnt  = deg[node];
    double acc0 = 0.0, acc1 = 0.0;
    int i = 0;
    for (; i + 2 <= cnt; i += 2) {
        int s0 = csr[base + i];
        int s1 = csr[base + i + 1];
        double2 p0 = ((const double2*)pack)[s0];   // {dinv, xw_s}
        double2 p1 = ((const double2*)pack)[s1];
        acc0 += p0.x * p0.y;
        acc1 += p1.x * p1.y;
    }
    if (i < cnt) {
        int s0 = csr[base + i];
        double2 p0 = ((const double2*)pack)[s0];
        acc0 += p0.x * p0.y;
    }
    score_sd[node] = pack[2 * node] * (acc0 + acc1);
}

// =============== K4: per-graph top-k (tanh finalize + bitonic, f64 keys) ===============

__global__ __launch_bounds__(512) void k4_topk(const double* __restrict__ score_sd,
                                               const double* __restrict__ pack,
                                               const double* __restrict__ sf,
                                               const float* __restrict__ bs,
                                               const int* __restrict__ batch,
                                               int* __restrict__ perm, int* __restrict__ nodemap,
                                               float* __restrict__ scoref_sel,
                                               float* __restrict__ out, long o2, long o3) {
    __shared__ double key[SORT_N];
    __shared__ int    idx[SORT_N];
    int g = blockIdx.x, t = threadIdx.x;
    const double A = 0.6, OMA = 1.0 - 0.6;
    double bsv = (double)bs[0];
    for (int i = t; i < SORT_N; i += 512) {
        if (i < NPGC) {
            int node = g * NPGC + i;
            double2 p = ((const double2*)pack)[node];   // {dinv, xw_s}
            double tot = score_sd[node] + p.x * p.x * p.y + bsv;  // + self loop + b_s
            key[i] = tanh(A * tot + OMA * sf[node]);
            idx[i] = i;
        } else { key[i] = -1e300; idx[i] = i; }
    }
    __syncthreads();
    for (int size = 2; size <= SORT_N; size <<= 1) {
        for (int stride = size >> 1; stride > 0; stride >>= 1) {
            int a = ((t & ~(stride - 1)) << 1) | (t & (stride - 1));
            int b = a | stride;
            bool descFirst = ((a & size) == 0);
            double ka = key[a], kb = key[b];
            int ia = idx[a], ib = idx[b];
            bool aAfterB = (ka < kb) || (ka == kb && ia > ib);  // stable descending
            if (descFirst ? aAfterB : !aAfterB) {
                key[a] = kb; key[b] = ka;
                idx[a] = ib; idx[b] = ia;
            }
            __syncthreads();
        }
    }
    for (int j = t; j < KSEL; j += 512) {
        int node = g * NPGC + idx[j];
        int pos  = g * KSEL + j;
        perm[pos]        = node;
        nodemap[node]    = pos + 1;             // 0 = unselected
        scoref_sel[pos]  = (float)key[j];
        out[o2 + pos]    = (float)batch[node];  // batch_out
        out[o3 + pos]    = (float)node;         // perm
    }
}

// =============== K5: edge flag+scan || fusion gather ===============

__global__ __launch_bounds__(256) void k5_escan_gather(const int* __restrict__ src,
                                                       const int* __restrict__ dst,
                                                       const int* __restrict__ nodemap,
                                                       int* __restrict__ epos,
                                                       int* __restrict__ bsumsE,
                                                       const float* __restrict__ xw,
                                                       const int* __restrict__ perm,
                                                       const int* __restrict__ rowoff,
                                                       const int* __restrict__ bsums256,
                                                       const int* __restrict__ deg,
                                                       const int* __restrict__ csr,
                                                       const float* __restrict__ dinvf,
                                                       const float* __restrict__ scoref_sel,
                                                       const float* __restrict__ b_fu,
                                                       float* __restrict__ out, long o4) {
    int t = threadIdx.x;
    int lane = t & 63, wid = t >> 6;
    if (blockIdx.x < NBE) {
        __shared__ int ws4[4];
        int base = blockIdx.x * 1024 + t * 4;
        int v0 = 0, v1 = 0, v2 = 0, v3 = 0;
        if (base + 0 < N_EDGES) v0 = (nodemap[src[base + 0]] > 0 && nodemap[dst[base + 0]] > 0);
        if (base + 1 < N_EDGES) v1 = (nodemap[src[base + 1]] > 0 && nodemap[dst[base + 1]] > 0);
        if (base + 2 < N_EDGES) v2 = (nodemap[src[base + 2]] > 0 && nodemap[dst[base + 2]] > 0);
        if (base + 3 < N_EDGES) v3 = (nodemap[src[base + 3]] > 0 && nodemap[dst[base + 3]] > 0);
        int s4 = v0 + v1 + v2 + v3;
        int incl = s4;
        #pragma unroll
        for (int off = 1; off < 64; off <<= 1) {
            int u = __shfl_up(incl, off, 64);
            if (lane >= off) incl += u;
        }
        if (lane == 63) ws4[wid] = incl;
        __syncthreads();
        int woff = 0;
        #pragma unroll
        for (int w = 0; w < 4; w++) if (w < wid) woff += ws4[w];
        int excl = incl - s4 + woff;
        if (base + 0 < N_EDGES) epos[base + 0] = excl;
        if (base + 1 < N_EDGES) epos[base + 1] = excl + v0;
        if (base + 2 < N_EDGES) epos[base + 2] = excl + v0 + v1;
        if (base + 3 < N_EDGES) epos[base + 3] = excl + v0 + v1 + v2;
        if (t == 255) bsumsE[blockIdx.x] = woff + incl;
        return;
    }
    __shared__ int bsN[256];
    if (t < 64) {
        int carry = 0;
        #pragma unroll
        for (int ch = 0; ch < 4; ch++) {
            int i = ch * 64 + t;
            int v = (i < NDINV) ? bsums256[i] : 0;
            int incl = v;
            #pragma unroll
            for (int off = 1; off < 64; off <<= 1) {
                int u = __shfl_up(incl, off, 64);
                if (t >= off) incl += u;
            }
            bsN[i] = incl - v + carry;
            carry += __shfl(incl, 63, 64);
        }
    }
    __syncthreads();
    int wave = (blockIdx.x - NBE) * 4 + wid;     // exactly 25000
    int p = perm[wave];
    float dpf = dinvf[p];
    int c2 = lane * 2;
    float2 v = ((const float2*)(xw + (size_t)p * DIM))[lane];
    float nself = dpf * dpf;
    float ax = nself * v.x, ay = nself * v.y;
    int beg = rowoff[p] + bsN[p >> 8], cnt = deg[p];
    int i = 0;
    for (; i + 2 <= cnt; i += 2) {
        int s0 = csr[beg + i];
        int s1 = csr[beg + i + 1];
        float2 u0 = ((const float2*)(xw + (size_t)s0 * DIM))[lane];
        float2 u1 = ((const float2*)(xw + (size_t)s1 * DIM))[lane];
        float n0 = dinvf[s0] * dpf, n1 = dinvf[s1] * dpf;
        ax += n0 * u0.x; ay += n0 * u0.y;
        ax += n1 * u1.x; ay += n1 * u1.y;
    }
    if (i < cnt) {
        int s0 = csr[beg + i];
        float2 u0 = ((const float2*)(xw + (size_t)s0 * DIM))[lane];
        float n0 = dinvf[s0] * dpf;
        ax += n0 * u0.x; ay += n0 * u0.y;
    }
    ax += b_fu[c2];
    ay += b_fu[c2 + 1];
    float sc = scoref_sel[wave];
    size_t ro = (size_t)wave * DIM + c2;
    out[o4 + ro]     = ax;        // x_ae
    out[o4 + ro + 1] = ay;
    out[ro]          = ax * sc;   // x_out
    out[ro + 1]      = ay * sc;
}

// =============== K6: edge compaction scatter (remap + write) ===============

__global__ __launch_bounds__(256) void k6_compact(const int* __restrict__ src,
                                                  const int* __restrict__ dst,
                                                  const int* __restrict__ nodemap,
                                                  const int* __restrict__ epos,
                                                  const int* __restrict__ bsumsE,
                                                  float* __restrict__ out_edges, long M) {
    __shared__ int bsE[512];
    int t = threadIdx.x;
    if (t < 64) {                               // wave 0: scan 489 entries, 8 chunks of 64
        int carry = 0;
        #pragma unroll
        for (int c = 0; c < 8; c++) {
            int i = c * 64 + t;
            int v = (i < NBE) ? bsumsE[i] : 0;
            int incl = v;
            #pragma unroll
            for (int off = 1; off < 64; off <<= 1) {
                int u = __shfl_up(incl, off, 64);
                if (t >= off) incl += u;
            }
            if (i < 512) bsE[i] = incl - v + carry;
            carry += __shfl(incl, 63, 64);
        }
    }
    __syncthreads();
    int e = blockIdx.x * 256 + t;
    if (e >= N_EDGES) return;
    int r = nodemap[src[e]], c = nodemap[dst[e]];
    if (r > 0 && c > 0) {
        int pos = epos[e] + bsE[e >> 10];
        out_edges[pos]     = (float)(r - 1);
        out_edges[M + pos] = (float)(c - 1);
    }
}

// ---------------- host ----------------

extern "C" void kernel_launch(void* const* d_in, const int* in_sizes, int n_in,
                              void* d_out, int out_size, void* d_ws, size_t ws_size,
                              hipStream_t stream) {
    const float* x    = (const float*)d_in[0];
    const int*   ei   = (const int*)d_in[1];
    const int*   src  = ei;
    const int*   dst  = ei + N_EDGES;
    const int*   batch= (const int*)d_in[2];
    const float* W_s  = (const float*)d_in[3];
    const float* b_s  = (const float*)d_in[4];
    const float* W_f  = (const float*)d_in[5];
    const float* b_f  = (const float*)d_in[6];
    const float* W_fu = (const float*)d_in[7];
    const float* b_fu = (const float*)d_in[8];
    float* out = (float*)d_out;

    char* wsp = (char*)d_ws;
    size_t off = 0;
    auto take = [&](size_t bytes) -> char* {
        char* p = wsp + off;
        off = (off + bytes + 255) & ~(size_t)255;
        return p;
    };
    // zero-cluster (single memset): degpriv | nodemap (0 = unselected)
    char*   zbase      = wsp;
    int*    degpriv    = (int*)   take((size_t)DEGB * N_NODES * 4);   // 12.8 MB
    int*    nodemap    = (int*)   take((size_t)N_NODES * 4);
    size_t  zbytes     = off;
    int*    eslot      = (int*)   take((size_t)N_EDGES * 4);
    int*    deg        = (int*)   take((size_t)N_NODES * 4);
    double* score_sd   = (double*)take((size_t)N_NODES * 8);
    double* pack       = (double*)take((size_t)N_NODES * 16);  // {dinv, xw_s} per node
    double* sf         = (double*)take((size_t)N_NODES * 8);
    float*  dinvf      = (float*) take((size_t)N_NODES * 4);
    float*  scoref_sel = (float*) take((size_t)NGRAPH * KSEL * 4);
    int*    perm       = (int*)   take((size_t)NGRAPH * KSEL * 4);
    int*    rowoff     = (int*)   take((size_t)N_NODES * 4);
    int*    epos       = (int*)   take((size_t)N_EDGES * 4);
    int*    bsumsE     = (int*)   take((size_t)1024 * 4);
    int*    bsums256   = (int*)   take((size_t)1024 * 4);
    int*    csr        = (int*)   take((size_t)N_EDGES * 4);
    float*  xw         = (float*) take((size_t)N_NODES * DIM * 4);

    // output layout: x_out[25000*128] | edge_index_new[2*M] | batch_out | perm | x_ae[25000*128]
    long M  = ((long)out_size - 6450000L) / 2;
    long o1 = 3200000L;
    long o2 = o1 + 2 * M;
    long o3 = o2 + (long)NGRAPH * KSEL;
    long o4 = o3 + (long)NGRAPH * KSEL;

    hipMemsetAsync(zbase, 0, zbytes, stream);

    k1b_deg<<<DEGB, 256, 0, stream>>>(dst, degpriv, eslot);
    k1a_gemm_dots<<<GEMM_BLKS, 256, 0, stream>>>(x, W_fu, xw, W_s, W_f, b_f, pack, sf);
    k2_merge<<<NDINV, 256, 0, stream>>>(degpriv, deg, rowoff, bsums256, pack, dinvf);
    k3_csr<<<EDGE_BLKS, 256, 0, stream>>>(src, dst, rowoff, bsums256, degpriv, eslot, csr);
    k3b_score<<<NDINV, 256, 0, stream>>>(csr, rowoff, bsums256, deg, pack, score_sd);
    k4_topk<<<NGRAPH, 512, 0, stream>>>(score_sd, pack, sf, b_s, batch,
                                        perm, nodemap, scoref_sel, out, o2, o3);
    k5_escan_gather<<<NBE + GATH_BLKS, 256, 0, stream>>>(src, dst, nodemap, epos, bsumsE,
                                                         xw, perm, rowoff, bsums256, deg, csr,
                                                         dinvf, scoref_sel, b_fu, out, o4);
    k6_compact<<<EDGE_BLKS, 256, 0, stream>>>(src, dst, nodemap, epos, bsumsE, out + o1, M);
}

// Round 6
// 209.950 us; speedup vs baseline: 1.1138x; 1.1138x over previous
//
#include <hip/hip_runtime.h>
#include <math.h>

#define N_NODES 50000
#define N_EDGES 500000
#define DIM     128
#define NGRAPH  50
#define NPGC    1000
#define KSEL    500
#define SORT_N  1024
#define NBE     489    // ceil(N_EDGES / 1024)
#define GEMM_BLKS 782  // ceil(N_NODES / 64)
#define EDGE_BLKS 1954 // ceil(N_EDGES / 256)
#define NDINV     196  // ceil(N_NODES / 256)
#define GATH_BLKS 6250
#define DEGB    64     // private-histogram deg blocks (workgroup-scope atomics)
#define NCHUNK  1954   // ceil(N_EDGES / 256) edge chunks, round-robin over DEGB blocks

// =============== K1: deg (private hist) || gemm k-quarter (25KB LDS) + fused dots ===============
// deg blocks [0,64): block b owns degpriv[b][N]; eslot[e] = within-(block,node) slot.
// gemm blocks [64,846): 64 nodes x 128 ch, W staged in k-QUARTERS (Wt 16KB + Xt 8KB
// + Ws/Wf 1KB = 25KB LDS -> 6 blocks/CU capacity; all 782 blocks co-resident, no
// tail round). FMA order identical to previous rounds (ascending k) -> bit-identical xw.

__global__ __launch_bounds__(256) void k1_fused(const float* __restrict__ x,
                                                const float* __restrict__ W,
                                                float* __restrict__ xw,
                                                const float* __restrict__ Ws,
                                                const float* __restrict__ Wf,
                                                const float* __restrict__ bf,
                                                double* __restrict__ pack,
                                                double* __restrict__ sf,
                                                const int* __restrict__ dst,
                                                int* __restrict__ degpriv,
                                                int* __restrict__ eslot) {
    __shared__ float lds[6400];             // Wt 4096 | Xt 2048 | Wsl 128 | Wfl 128 (25KB)
    int t = threadIdx.x;
    if (blockIdx.x < DEGB) {
        int b = blockIdx.x;
        int* priv = degpriv + b * N_NODES;
        for (int c = b; c < NCHUNK; c += 2 * DEGB) {
            int e1 = (c << 8) + t;
            int cB = c + DEGB;
            int e2 = (cB << 8) + t;
            int d1 = (e1 < N_EDGES) ? dst[e1] : -1;
            int d2 = (cB < NCHUNK && e2 < N_EDGES) ? dst[e2] : -1;
            if (d1 >= 0)
                eslot[e1] = __hip_atomic_fetch_add(&priv[d1], 1, __ATOMIC_RELAXED,
                                                   __HIP_MEMORY_SCOPE_WORKGROUP);
            if (d2 >= 0)
                eslot[e2] = __hip_atomic_fetch_add(&priv[d2], 1, __ATOMIC_RELAXED,
                                                   __HIP_MEMORY_SCOPE_WORKGROUP);
        }
        return;
    }
    float* Wt  = lds;                       // [k(32)][ch(128)]
    float* Xt  = lds + 4096;                // [node(64)][k(32)], XOR-swizzled float4 cols
    float* Wsl = lds + 6144;                // Ws staged (128)
    float* Wfl = lds + 6272;                // Wf staged (128)
    int cg = t & 15;
    int ng = t >> 4;
    int node_base = (blockIdx.x - DEGB) * 64;

    if (t < 128) Wsl[t] = Ws[t];
    else         Wfl[t - 128] = Wf[t - 128];

    // fused-dot state: 4 threads per node, each owns 8 k's per quarter
    int dn  = t >> 2;                       // node row 0..63
    int dk8 = (t & 3) << 3;                 // k offset within quarter: 0/8/16/24
    double ps = 0.0, pf = 0.0;

    float4 acc[4][2];
    #pragma unroll
    for (int nn = 0; nn < 4; nn++) {
        acc[nn][0] = make_float4(0.f, 0.f, 0.f, 0.f);
        acc[nn][1] = make_float4(0.f, 0.f, 0.f, 0.f);
    }
    for (int qtr = 0; qtr < 4; qtr++) {
        const float4* Wg = (const float4*)W + qtr * 1024;   // 32 k-rows x 32 float4
        float4* Wl = (float4*)Wt;
        #pragma unroll
        for (int i = 0; i < 4; i++) {
            int f = t + i * 256;
            Wl[f] = Wg[f];
        }
        #pragma unroll
        for (int i = 0; i < 2; i++) {
            int f = t + i * 256;            // 512 float4 = 64 rows x 8
            int row = f >> 3, col = f & 7;
            int node = node_base + row;
            float4 v = make_float4(0.f, 0.f, 0.f, 0.f);
            if (node < N_NODES) v = *(const float4*)&x[(size_t)node * DIM + qtr * 32 + col * 4];
            *(float4*)&Xt[(row << 5) + ((col ^ (row & 7)) << 2)] = v;
        }
        __syncthreads();
        #pragma unroll 2
        for (int kc = 0; kc < 8; kc++) {
            int k = kc << 2;
            float4 wa[4], wb[4];
            #pragma unroll
            for (int kk = 0; kk < 4; kk++) {
                wa[kk] = *(const float4*)&Wt[(k + kk) * DIM + (cg << 2)];
                wb[kk] = *(const float4*)&Wt[(k + kk) * DIM + (cg << 2) + 64];
            }
            int csw = (kc ^ (ng & 7)) << 2;
            #pragma unroll
            for (int nn = 0; nn < 4; nn++) {
                float4 xv = *(const float4*)&Xt[((ng + (nn << 4)) << 5) + csw];
                acc[nn][0].x += xv.x * wa[0].x + xv.y * wa[1].x + xv.z * wa[2].x + xv.w * wa[3].x;
                acc[nn][0].y += xv.x * wa[0].y + xv.y * wa[1].y + xv.z * wa[2].y + xv.w * wa[3].y;
                acc[nn][0].z += xv.x * wa[0].z + xv.y * wa[1].z + xv.z * wa[2].z + xv.w * wa[3].z;
                acc[nn][0].w += xv.x * wa[0].w + xv.y * wa[1].w + xv.z * wa[2].w + xv.w * wa[3].w;
                acc[nn][1].x += xv.x * wb[0].x + xv.y * wb[1].x + xv.z * wb[2].x + xv.w * wb[3].x;
                acc[nn][1].y += xv.x * wb[0].y + xv.y * wb[1].y + xv.z * wb[2].y + xv.w * wb[3].y;
                acc[nn][1].z += xv.x * wb[0].z + xv.y * wb[1].z + xv.z * wb[2].z + xv.w * wb[3].z;
                acc[nn][1].w += xv.x * wb[0].w + xv.y * wb[1].w + xv.z * wb[2].w + xv.w * wb[3].w;
            }
        }
        // fused dots for this quarter: read own node's staged x from Xt (swizzled)
        #pragma unroll 4
        for (int j = 0; j < 8; j++) {
            int ko = dk8 + j;               // 0..31 within quarter
            int col = ko >> 2, sub = ko & 3;
            double xd = (double)Xt[(dn << 5) + ((col ^ (dn & 7)) << 2) + sub];
            ps += xd * (double)Wsl[qtr * 32 + ko];
            pf += xd * (double)Wfl[qtr * 32 + ko];
        }
        __syncthreads();
    }
    #pragma unroll
    for (int nn = 0; nn < 4; nn++) {
        int node = node_base + ng + (nn << 4);
        if (node < N_NODES) {
            *(float4*)&xw[(size_t)node * DIM + (cg << 2)]      = acc[nn][0];
            *(float4*)&xw[(size_t)node * DIM + (cg << 2) + 64] = acc[nn][1];
        }
    }
    // reduce dots across the 4 lanes of each node group, write pack/sf
    ps += __shfl_down(ps, 2, 64); ps += __shfl_down(ps, 1, 64);
    pf += __shfl_down(pf, 2, 64); pf += __shfl_down(pf, 1, 64);
    if ((t & 3) == 0) {
        int node = node_base + dn;
        if (node < N_NODES) {
            pack[2 * node + 1] = ps;        // xw_s
            sf[node] = pf + (double)bf[0];
        }
    }
}

// =============== K2: merge(deg, blockoff in-place) + dinv + rowoff scan ===============

__global__ __launch_bounds__(256) void k2_merge(int* __restrict__ degpriv,
                                                int* __restrict__ deg,
                                                int* __restrict__ rowoff,
                                                int* __restrict__ bsums256,
                                                double* __restrict__ pack,
                                                float* __restrict__ dinvf) {
    int t = threadIdx.x;
    int lane = t & 63, wid = t >> 6;
    int i = blockIdx.x * 256 + t;
    int o = 0;
    if (i < N_NODES) {
        #pragma unroll 8
        for (int b = 0; b < DEGB; b++) {
            int* p = &degpriv[b * N_NODES + i];
            int c = *p;
            *p = o;                              // exclusive prefix across blocks, in place
            o += c;
        }
        deg[i] = o;                              // total in-degree
        double di = 1.0 / sqrt((double)(o + 1));
        pack[2 * i] = di;
        dinvf[i] = (float)di;
    }
    __shared__ int ws4[4];
    int incl = o;
    #pragma unroll
    for (int off = 1; off < 64; off <<= 1) {
        int u = __shfl_up(incl, off, 64);
        if (lane >= off) incl += u;
    }
    if (lane == 63) ws4[wid] = incl;
    __syncthreads();
    int woff = 0;
    #pragma unroll
    for (int w = 0; w < 4; w++) if (w < wid) woff += ws4[w];
    if (i < N_NODES) rowoff[i] = incl - o + woff;
    if (t == 255) bsums256[blockIdx.x] = woff + incl;
}

// =============== K3: CSR fill, atomic-free ===============

__global__ __launch_bounds__(256) void k3_csr(const int* __restrict__ src,
                                              const int* __restrict__ dst,
                                              const int* __restrict__ rowoff,
                                              const int* __restrict__ bsums256,
                                              const int* __restrict__ degpriv,
                                              const int* __restrict__ eslot,
                                              int* __restrict__ csr) {
    __shared__ int bsN[256];
    int t = threadIdx.x;
    if (t < 64) {                               // one wave: scan 196 block sums, 4 chunks
        int carry = 0;
        #pragma unroll
        for (int ch = 0; ch < 4; ch++) {
            int i = ch * 64 + t;
            int v = (i < NDINV) ? bsums256[i] : 0;
            int incl = v;
            #pragma unroll
            for (int off = 1; off < 64; off <<= 1) {
                int u = __shfl_up(incl, off, 64);
                if (t >= off) incl += u;
            }
            bsN[i] = incl - v + carry;
            carry += __shfl(incl, 63, 64);
        }
    }
    __syncthreads();
    int e = blockIdx.x * 256 + t;
    if (e >= N_EDGES) return;
    int d = dst[e];
    int owner = (e >> 8) & (DEGB - 1);
    int pos = rowoff[d] + bsN[d >> 8] + degpriv[owner * N_NODES + d] + eslot[e];
    csr[pos] = src[e];
}

// =============== K3b: structure score via CSR gather (no atomics, f64) ===============

__global__ __launch_bounds__(256) void k3b_score(const int* __restrict__ csr,
                                                 const int* __restrict__ rowoff,
                                                 const int* __restrict__ bsums256,
                                                 const int* __restrict__ deg,
                                                 const double* __restrict__ pack,
                                                 double* __restrict__ score_sd) {
    __shared__ int bsN[256];
    int t = threadIdx.x;
    if (t < 64) {
        int carry = 0;
        #pragma unroll
        for (int ch = 0; ch < 4; ch++) {
            int i = ch * 64 + t;
            int v = (i < NDINV) ? bsums256[i] : 0;
            int incl = v;
            #pragma unroll
            for (int off = 1; off < 64; off <<= 1) {
                int u = __shfl_up(incl, off, 64);
                if (t >= off) incl += u;
            }
            bsN[i] = incl - v + carry;
            carry += __shfl(incl, 63, 64);
        }
    }
    __syncthreads();
    int node = blockIdx.x * 256 + t;
    if (node >= N_NODES) return;
    int base = rowoff[node] + bsN[node >> 8];
    int cnt  = deg[node];
    double acc0 = 0.0, acc1 = 0.0;
    int i = 0;
    for (; i + 2 <= cnt; i += 2) {
        int s0 = csr[base + i];
        int s1 = csr[base + i + 1];
        double2 p0 = ((const double2*)pack)[s0];   // {dinv, xw_s}
        double2 p1 = ((const double2*)pack)[s1];
        acc0 += p0.x * p0.y;
        acc1 += p1.x * p1.y;
    }
    if (i < cnt) {
        int s0 = csr[base + i];
        double2 p0 = ((const double2*)pack)[s0];
        acc0 += p0.x * p0.y;
    }
    score_sd[node] = pack[2 * node] * (acc0 + acc1);
}

// =============== K4: per-graph top-k (tanh finalize + bitonic, f64 keys) ===============

__global__ __launch_bounds__(512) void k4_topk(const double* __restrict__ score_sd,
                                               const double* __restrict__ pack,
                                               const double* __restrict__ sf,
                                               const float* __restrict__ bs,
                                               const int* __restrict__ batch,
                                               int* __restrict__ perm, int* __restrict__ nodemap,
                                               float* __restrict__ scoref_sel,
                                               float* __restrict__ out, long o2, long o3) {
    __shared__ double key[SORT_N];
    __shared__ int    idx[SORT_N];
    int g = blockIdx.x, t = threadIdx.x;
    const double A = 0.6, OMA = 1.0 - 0.6;
    double bsv = (double)bs[0];
    for (int i = t; i < SORT_N; i += 512) {
        if (i < NPGC) {
            int node = g * NPGC + i;
            double2 p = ((const double2*)pack)[node];   // {dinv, xw_s}
            double tot = score_sd[node] + p.x * p.x * p.y + bsv;  // + self loop + b_s
            key[i] = tanh(A * tot + OMA * sf[node]);
            idx[i] = i;
        } else { key[i] = -1e300; idx[i] = i; }
    }
    __syncthreads();
    for (int size = 2; size <= SORT_N; size <<= 1) {
        for (int stride = size >> 1; stride > 0; stride >>= 1) {
            int a = ((t & ~(stride - 1)) << 1) | (t & (stride - 1));
            int b = a | stride;
            bool descFirst = ((a & size) == 0);
            double ka = key[a], kb = key[b];
            int ia = idx[a], ib = idx[b];
            bool aAfterB = (ka < kb) || (ka == kb && ia > ib);  // stable descending
            if (descFirst ? aAfterB : !aAfterB) {
                key[a] = kb; key[b] = ka;
                idx[a] = ib; idx[b] = ia;
            }
            __syncthreads();
        }
    }
    for (int j = t; j < KSEL; j += 512) {
        int node = g * NPGC + idx[j];
        int pos  = g * KSEL + j;
        perm[pos]        = node;
        nodemap[node]    = pos + 1;             // 0 = unselected
        scoref_sel[pos]  = (float)key[j];
        out[o2 + pos]    = (float)batch[node];  // batch_out
        out[o3 + pos]    = (float)node;         // perm
    }
}

// =============== K5: edge flag+scan || fusion gather ===============

__global__ __launch_bounds__(256) void k5_escan_gather(const int* __restrict__ src,
                                                       const int* __restrict__ dst,
                                                       const int* __restrict__ nodemap,
                                                       int* __restrict__ epos,
                                                       int* __restrict__ bsumsE,
                                                       const float* __restrict__ xw,
                                                       const int* __restrict__ perm,
                                                       const int* __restrict__ rowoff,
                                                       const int* __restrict__ bsums256,
                                                       const int* __restrict__ deg,
                                                       const int* __restrict__ csr,
                                                       const float* __restrict__ dinvf,
                                                       const float* __restrict__ scoref_sel,
                                                       const float* __restrict__ b_fu,
                                                       float* __restrict__ out, long o4) {
    int t = threadIdx.x;
    int lane = t & 63, wid = t >> 6;
    if (blockIdx.x < NBE) {
        __shared__ int ws4[4];
        int base = blockIdx.x * 1024 + t * 4;
        int v0 = 0, v1 = 0, v2 = 0, v3 = 0;
        if (base + 0 < N_EDGES) v0 = (nodemap[src[base + 0]] > 0 && nodemap[dst[base + 0]] > 0);
        if (base + 1 < N_EDGES) v1 = (nodemap[src[base + 1]] > 0 && nodemap[dst[base + 1]] > 0);
        if (base + 2 < N_EDGES) v2 = (nodemap[src[base + 2]] > 0 && nodemap[dst[base + 2]] > 0);
        if (base + 3 < N_EDGES) v3 = (nodemap[src[base + 3]] > 0 && nodemap[dst[base + 3]] > 0);
        int s4 = v0 + v1 + v2 + v3;
        int incl = s4;
        #pragma unroll
        for (int off = 1; off < 64; off <<= 1) {
            int u = __shfl_up(incl, off, 64);
            if (lane >= off) incl += u;
        }
        if (lane == 63) ws4[wid] = incl;
        __syncthreads();
        int woff = 0;
        #pragma unroll
        for (int w = 0; w < 4; w++) if (w < wid) woff += ws4[w];
        int excl = incl - s4 + woff;
        if (base + 0 < N_EDGES) epos[base + 0] = excl;
        if (base + 1 < N_EDGES) epos[base + 1] = excl + v0;
        if (base + 2 < N_EDGES) epos[base + 2] = excl + v0 + v1;
        if (base + 3 < N_EDGES) epos[base + 3] = excl + v0 + v1 + v2;
        if (t == 255) bsumsE[blockIdx.x] = woff + incl;
        return;
    }
    __shared__ int bsN[256];
    if (t < 64) {
        int carry = 0;
        #pragma unroll
        for (int ch = 0; ch < 4; ch++) {
            int i = ch * 64 + t;
            int v = (i < NDINV) ? bsums256[i] : 0;
            int incl = v;
            #pragma unroll
            for (int off = 1; off < 64; off <<= 1) {
                int u = __shfl_up(incl, off, 64);
                if (t >= off) incl += u;
            }
            bsN[i] = incl - v + carry;
            carry += __shfl(incl, 63, 64);
        }
    }
    __syncthreads();
    int wave = (blockIdx.x - NBE) * 4 + wid;     // exactly 25000
    int p = perm[wave];
    float dpf = dinvf[p];
    int c2 = lane * 2;
    float2 v = ((const float2*)(xw + (size_t)p * DIM))[lane];
    float nself = dpf * dpf;
    float ax = nself * v.x, ay = nself * v.y;
    int beg = rowoff[p] + bsN[p >> 8], cnt = deg[p];
    int i = 0;
    for (; i + 2 <= cnt; i += 2) {
        int s0 = csr[beg + i];
        int s1 = csr[beg + i + 1];
        float2 u0 = ((const float2*)(xw + (size_t)s0 * DIM))[lane];
        float2 u1 = ((const float2*)(xw + (size_t)s1 * DIM))[lane];
        float n0 = dinvf[s0] * dpf, n1 = dinvf[s1] * dpf;
        ax += n0 * u0.x; ay += n0 * u0.y;
        ax += n1 * u1.x; ay += n1 * u1.y;
    }
    if (i < cnt) {
        int s0 = csr[beg + i];
        float2 u0 = ((const float2*)(xw + (size_t)s0 * DIM))[lane];
        float n0 = dinvf[s0] * dpf;
        ax += n0 * u0.x; ay += n0 * u0.y;
    }
    ax += b_fu[c2];
    ay += b_fu[c2 + 1];
    float sc = scoref_sel[wave];
    size_t ro = (size_t)wave * DIM + c2;
    out[o4 + ro]     = ax;        // x_ae
    out[o4 + ro + 1] = ay;
    out[ro]          = ax * sc;   // x_out
    out[ro + 1]      = ay * sc;
}

// =============== K6: edge compaction scatter (remap + write) ===============

__global__ __launch_bounds__(256) void k6_compact(const int* __restrict__ src,
                                                  const int* __restrict__ dst,
                                                  const int* __restrict__ nodemap,
                                                  const int* __restrict__ epos,
                                                  const int* __restrict__ bsumsE,
                                                  float* __restrict__ out_edges, long M) {
    __shared__ int bsE[512];
    int t = threadIdx.x;
    if (t < 64) {                               // wave 0: scan 489 entries, 8 chunks of 64
        int carry = 0;
        #pragma unroll
        for (int c = 0; c < 8; c++) {
            int i = c * 64 + t;
            int v = (i < NBE) ? bsumsE[i] : 0;
            int incl = v;
            #pragma unroll
            for (int off = 1; off < 64; off <<= 1) {
                int u = __shfl_up(incl, off, 64);
                if (t >= off) incl += u;
            }
            if (i < 512) bsE[i] = incl - v + carry;
            carry += __shfl(incl, 63, 64);
        }
    }
    __syncthreads();
    int e = blockIdx.x * 256 + t;
    if (e >= N_EDGES) return;
    int r = nodemap[src[e]], c = nodemap[dst[e]];
    if (r > 0 && c > 0) {
        int pos = epos[e] + bsE[e >> 10];
        out_edges[pos]     = (float)(r - 1);
        out_edges[M + pos] = (float)(c - 1);
    }
}

// ---------------- host ----------------

extern "C" void kernel_launch(void* const* d_in, const int* in_sizes, int n_in,
                              void* d_out, int out_size, void* d_ws, size_t ws_size,
                              hipStream_t stream) {
    const float* x    = (const float*)d_in[0];
    const int*   ei   = (const int*)d_in[1];
    const int*   src  = ei;
    const int*   dst  = ei + N_EDGES;
    const int*   batch= (const int*)d_in[2];
    const float* W_s  = (const float*)d_in[3];
    const float* b_s  = (const float*)d_in[4];
    const float* W_f  = (const float*)d_in[5];
    const float* b_f  = (const float*)d_in[6];
    const float* W_fu = (const float*)d_in[7];
    const float* b_fu = (const float*)d_in[8];
    float* out = (float*)d_out;

    char* wsp = (char*)d_ws;
    size_t off = 0;
    auto take = [&](size_t bytes) -> char* {
        char* p = wsp + off;
        off = (off + bytes + 255) & ~(size_t)255;
        return p;
    };
    // zero-cluster (single memset): degpriv | nodemap (0 = unselected)
    char*   zbase      = wsp;
    int*    degpriv    = (int*)   take((size_t)DEGB * N_NODES * 4);   // 12.8 MB
    int*    nodemap    = (int*)   take((size_t)N_NODES * 4);
    size_t  zbytes     = off;
    int*    eslot      = (int*)   take((size_t)N_EDGES * 4);
    int*    deg        = (int*)   take((size_t)N_NODES * 4);
    double* score_sd   = (double*)take((size_t)N_NODES * 8);
    double* pack       = (double*)take((size_t)N_NODES * 16);  // {dinv, xw_s} per node
    double* sf         = (double*)take((size_t)N_NODES * 8);
    float*  dinvf      = (float*) take((size_t)N_NODES * 4);
    float*  scoref_sel = (float*) take((size_t)NGRAPH * KSEL * 4);
    int*    perm       = (int*)   take((size_t)NGRAPH * KSEL * 4);
    int*    rowoff     = (int*)   take((size_t)N_NODES * 4);
    int*    epos       = (int*)   take((size_t)N_EDGES * 4);
    int*    bsumsE     = (int*)   take((size_t)1024 * 4);
    int*    bsums256   = (int*)   take((size_t)1024 * 4);
    int*    csr        = (int*)   take((size_t)N_EDGES * 4);
    float*  xw         = (float*) take((size_t)N_NODES * DIM * 4);

    // output layout: x_out[25000*128] | edge_index_new[2*M] | batch_out | perm | x_ae[25000*128]
    long M  = ((long)out_size - 6450000L) / 2;
    long o1 = 3200000L;
    long o2 = o1 + 2 * M;
    long o3 = o2 + (long)NGRAPH * KSEL;
    long o4 = o3 + (long)NGRAPH * KSEL;

    hipMemsetAsync(zbase, 0, zbytes, stream);

    k1_fused<<<DEGB + GEMM_BLKS, 256, 0, stream>>>(x, W_fu, xw, W_s, W_f, b_f, pack, sf,
                                                   dst, degpriv, eslot);
    k2_merge<<<NDINV, 256, 0, stream>>>(degpriv, deg, rowoff, bsums256, pack, dinvf);
    k3_csr<<<EDGE_BLKS, 256, 0, stream>>>(src, dst, rowoff, bsums256, degpriv, eslot, csr);
    k3b_score<<<NDINV, 256, 0, stream>>>(csr, rowoff, bsums256, deg, pack, score_sd);
    k4_topk<<<NGRAPH, 512, 0, stream>>>(score_sd, pack, sf, b_s, batch,
                                        perm, nodemap, scoref_sel, out, o2, o3);
    k5_escan_gather<<<NBE + GATH_BLKS, 256, 0, stream>>>(src, dst, nodemap, epos, bsumsE,
                                                         xw, perm, rowoff, bsums256, deg, csr,
                                                         dinvf, scoref_sel, b_fu, out, o4);
    k6_compact<<<EDGE_BLKS, 256, 0, stream>>>(src, dst, nodemap, epos, bsumsE, out + o1, M);
}

// Round 7
// 209.044 us; speedup vs baseline: 1.1187x; 1.0043x over previous
//
#include <hip/hip_runtime.h>
#include <math.h>

#define N_NODES 50000
#define N_EDGES 500000
#define DIM     128
#define NGRAPH  50
#define NPGC    1000
#define KSEL    500
#define SORT_N  1024
#define NBE     489    // ceil(N_EDGES / 1024)
#define GEMM_BLKS 782  // ceil(N_NODES / 64)
#define EDGE_BLKS 1954 // ceil(N_EDGES / 256)
#define NDINV     196  // ceil(N_NODES / 256)
#define GATH_BLKS 6250
#define DEGB    64     // private-histogram deg blocks (workgroup-scope atomics)
#define NCHUNK  1954   // ceil(N_EDGES / 256) edge chunks, round-robin over DEGB blocks

using bfrag = __attribute__((ext_vector_type(8))) short;   // 8 bf16 (4 VGPRs)
using f32x4 = __attribute__((ext_vector_type(4))) float;   // MFMA accumulator

__device__ __forceinline__ unsigned short f2bf(float f) {  // RTNE f32->bf16
    unsigned int u = __float_as_uint(f);
    u += 0x7FFF + ((u >> 16) & 1);
    return (unsigned short)(u >> 16);
}
__device__ __forceinline__ float bf2f(unsigned short h) {
    return __uint_as_float(((unsigned int)h) << 16);
}

// =============== K1: deg (private hist) || bf16-split MFMA gemm + fused dots ===============
// deg blocks [0,64): unchanged. gemm blocks [64,846): 64 nodes x 128 ch, K in quarters.
// xw = x@W via 3-term bf16 split (hi*hi + hi*lo + lo*hi), f32 MFMA accum; error ~1e-4.
// LDS: Wt transposed [ch][k] hi/lo + X [node][k] hi/lo, rows padded to 40 bf16 (80B).
// A/B k-order assumptions cancel (same map both operands); C/D map = m89-verified.

__global__ __launch_bounds__(256) void k1_fused(const float* __restrict__ x,
                                                const float* __restrict__ W,
                                                float* __restrict__ xw,
                                                const float* __restrict__ Ws,
                                                const float* __restrict__ Wf,
                                                const float* __restrict__ bf,
                                                double* __restrict__ pack,
                                                double* __restrict__ sf,
                                                const int* __restrict__ dst,
                                                int* __restrict__ degpriv,
                                                int* __restrict__ eslot) {
    __shared__ unsigned short uls[15360];  // Wth 5120 | Wtl 5120 | Xh 2560 | Xl 2560 (30KB)
    __shared__ float wsf[256];             // Ws | Wf staged
    int t = threadIdx.x;
    if (blockIdx.x < DEGB) {
        int b = blockIdx.x;
        int* priv = degpriv + b * N_NODES;
        for (int c = b; c < NCHUNK; c += 2 * DEGB) {
            int e1 = (c << 8) + t;
            int cB = c + DEGB;
            int e2 = (cB << 8) + t;
            int d1 = (e1 < N_EDGES) ? dst[e1] : -1;
            int d2 = (cB < NCHUNK && e2 < N_EDGES) ? dst[e2] : -1;
            if (d1 >= 0)
                eslot[e1] = __hip_atomic_fetch_add(&priv[d1], 1, __ATOMIC_RELAXED,
                                                   __HIP_MEMORY_SCOPE_WORKGROUP);
            if (d2 >= 0)
                eslot[e2] = __hip_atomic_fetch_add(&priv[d2], 1, __ATOMIC_RELAXED,
                                                   __HIP_MEMORY_SCOPE_WORKGROUP);
        }
        return;
    }
    unsigned short* Wth = uls;             // [128 ch][40], k 0..31 of quarter
    unsigned short* Wtl = uls + 5120;
    unsigned short* Xh  = uls + 10240;     // [64 node][40]
    unsigned short* Xl  = uls + 12800;
    int node_base = (blockIdx.x - DEGB) * 64;
    int l = t & 63, wv = t >> 6;
    int arow = l & 15;                     // A row / B col within 16-tile
    int ag   = l >> 4;                     // k-group (x8 elems)

    if (t < 128) wsf[t] = Ws[t];
    else         wsf[t] = Wf[t - 128];

    int dn = t >> 2, dq = t & 3;           // dots: 4 threads/node, 8 k each per quarter
    double ps = 0.0, pf = 0.0;

    f32x4 acc[8];
    #pragma unroll
    for (int cg = 0; cg < 8; cg++) { f32x4 z = {0.f, 0.f, 0.f, 0.f}; acc[cg] = z; }

    for (int qtr = 0; qtr < 4; qtr++) {
        // stage W quarter, transposed + split (coalesced global, u32 LDS writes)
        #pragma unroll
        for (int i = 0; i < 8; i++) {
            int f = t + (i << 8);          // 0..2047
            int ch = f & 127, k2 = f >> 7; // k2 = k-pair 0..15
            float w0 = W[(size_t)(qtr * 32 + k2 * 2)     * DIM + ch];
            float w1 = W[(size_t)(qtr * 32 + k2 * 2 + 1) * DIM + ch];
            unsigned short h0 = f2bf(w0), h1 = f2bf(w1);
            unsigned short l0 = f2bf(w0 - bf2f(h0)), l1 = f2bf(w1 - bf2f(h1));
            *(unsigned int*)&Wth[ch * 40 + k2 * 2] = (unsigned int)h0 | ((unsigned int)h1 << 16);
            *(unsigned int*)&Wtl[ch * 40 + k2 * 2] = (unsigned int)l0 | ((unsigned int)l1 << 16);
        }
        // stage x quarter, split
        #pragma unroll
        for (int i = 0; i < 2; i++) {
            int f = t + (i << 8);          // 0..511 = 64 rows x 8 float4
            int row = f >> 3, col = f & 7;
            int node = node_base + row;
            float4 v = make_float4(0.f, 0.f, 0.f, 0.f);
            if (node < N_NODES) v = *(const float4*)&x[(size_t)node * DIM + qtr * 32 + col * 4];
            unsigned short h0 = f2bf(v.x), h1 = f2bf(v.y), h2 = f2bf(v.z), h3 = f2bf(v.w);
            unsigned short g0 = f2bf(v.x - bf2f(h0)), g1 = f2bf(v.y - bf2f(h1));
            unsigned short g2 = f2bf(v.z - bf2f(h2)), g3 = f2bf(v.w - bf2f(h3));
            ushort4 hv; hv.x = h0; hv.y = h1; hv.z = h2; hv.w = h3;
            ushort4 lv; lv.x = g0; lv.y = g1; lv.z = g2; lv.w = g3;
            *(ushort4*)&Xh[row * 40 + col * 4] = hv;
            *(ushort4*)&Xl[row * 40 + col * 4] = lv;
        }
        __syncthreads();
        // MFMA: wave wv owns nodes [wv*16, wv*16+16), all 8 ch-groups
        bfrag ah = *(const bfrag*)&Xh[(wv * 16 + arow) * 40 + ag * 8];
        bfrag al = *(const bfrag*)&Xl[(wv * 16 + arow) * 40 + ag * 8];
        #pragma unroll
        for (int cg = 0; cg < 8; cg++) {
            bfrag bh = *(const bfrag*)&Wth[(cg * 16 + arow) * 40 + ag * 8];
            bfrag bl = *(const bfrag*)&Wtl[(cg * 16 + arow) * 40 + ag * 8];
            acc[cg] = __builtin_amdgcn_mfma_f32_16x16x32_bf16(ah, bh, acc[cg], 0, 0, 0);
            acc[cg] = __builtin_amdgcn_mfma_f32_16x16x32_bf16(ah, bl, acc[cg], 0, 0, 0);
            acc[cg] = __builtin_amdgcn_mfma_f32_16x16x32_bf16(al, bh, acc[cg], 0, 0, 0);
        }
        // fused dots: reconstruct x = hi + lo (error ~2^-18, can't flip top-k order)
        {
            bfrag xh = *(const bfrag*)&Xh[dn * 40 + dq * 8];
            bfrag xl = *(const bfrag*)&Xl[dn * 40 + dq * 8];
            #pragma unroll
            for (int j = 0; j < 8; j++) {
                double xd = (double)bf2f((unsigned short)xh[j])
                          + (double)bf2f((unsigned short)xl[j]);
                int k = qtr * 32 + dq * 8 + j;
                ps += xd * (double)wsf[k];
                pf += xd * (double)wsf[128 + k];
            }
        }
        __syncthreads();
    }
    // C store: D row = (l>>4)*4 + j, col = l&15 (m89-verified)
    int r0 = wv * 16 + ((l >> 4) << 2);
    int c0 = l & 15;
    #pragma unroll
    for (int cg = 0; cg < 8; cg++) {
        #pragma unroll
        for (int j = 0; j < 4; j++) {
            int node = node_base + r0 + j;
            if (node < N_NODES) xw[(size_t)node * DIM + cg * 16 + c0] = acc[cg][j];
        }
    }
    // dot reduce across 4 lanes per node
    ps += __shfl_down(ps, 2, 64); ps += __shfl_down(ps, 1, 64);
    pf += __shfl_down(pf, 2, 64); pf += __shfl_down(pf, 1, 64);
    if ((t & 3) == 0) {
        int node = node_base + dn;
        if (node < N_NODES) {
            pack[2 * node + 1] = ps;        // xw_s
            sf[node] = pf + (double)bf[0];
        }
    }
}

// =============== K2: merge(deg, blockoff in-place) + dinv + rowoff scan ===============

__global__ __launch_bounds__(256) void k2_merge(int* __restrict__ degpriv,
                                                int* __restrict__ deg,
                                                int* __restrict__ rowoff,
                                                int* __restrict__ bsums256,
                                                double* __restrict__ pack,
                                                float* __restrict__ dinvf) {
    int t = threadIdx.x;
    int lane = t & 63, wid = t >> 6;
    int i = blockIdx.x * 256 + t;
    int o = 0;
    if (i < N_NODES) {
        #pragma unroll 8
        for (int b = 0; b < DEGB; b++) {
            int* p = &degpriv[b * N_NODES + i];
            int c = *p;
            *p = o;                              // exclusive prefix across blocks, in place
            o += c;
        }
        deg[i] = o;                              // total in-degree
        double di = 1.0 / sqrt((double)(o + 1));
        pack[2 * i] = di;
        dinvf[i] = (float)di;
    }
    __shared__ int ws4[4];
    int incl = o;
    #pragma unroll
    for (int off = 1; off < 64; off <<= 1) {
        int u = __shfl_up(incl, off, 64);
        if (lane >= off) incl += u;
    }
    if (lane == 63) ws4[wid] = incl;
    __syncthreads();
    int woff = 0;
    #pragma unroll
    for (int w = 0; w < 4; w++) if (w < wid) woff += ws4[w];
    if (i < N_NODES) rowoff[i] = incl - o + woff;
    if (t == 255) bsums256[blockIdx.x] = woff + incl;
}

// =============== K3: CSR fill, atomic-free ===============

__global__ __launch_bounds__(256) void k3_csr(const int* __restrict__ src,
                                              const int* __restrict__ dst,
                                              const int* __restrict__ rowoff,
                                              const int* __restrict__ bsums256,
                                              const int* __restrict__ degpriv,
                                              const int* __restrict__ eslot,
                                              int* __restrict__ csr) {
    __shared__ int bsN[256];
    int t = threadIdx.x;
    if (t < 64) {                               // one wave: scan 196 block sums, 4 chunks
        int carry = 0;
        #pragma unroll
        for (int ch = 0; ch < 4; ch++) {
            int i = ch * 64 + t;
            int v = (i < NDINV) ? bsums256[i] : 0;
            int incl = v;
            #pragma unroll
            for (int off = 1; off < 64; off <<= 1) {
                int u = __shfl_up(incl, off, 64);
                if (t >= off) incl += u;
            }
            bsN[i] = incl - v + carry;
            carry += __shfl(incl, 63, 64);
        }
    }
    __syncthreads();
    int e = blockIdx.x * 256 + t;
    if (e >= N_EDGES) return;
    int d = dst[e];
    int owner = (e >> 8) & (DEGB - 1);
    int pos = rowoff[d] + bsN[d >> 8] + degpriv[owner * N_NODES + d] + eslot[e];
    csr[pos] = src[e];
}

// =============== K3b: structure score via CSR gather (no atomics, f64) ===============

__global__ __launch_bounds__(256) void k3b_score(const int* __restrict__ csr,
                                                 const int* __restrict__ rowoff,
                                                 const int* __restrict__ bsums256,
                                                 const int* __restrict__ deg,
                                                 const double* __restrict__ pack,
                                                 double* __restrict__ score_sd) {
    __shared__ int bsN[256];
    int t = threadIdx.x;
    if (t < 64) {
        int carry = 0;
        #pragma unroll
        for (int ch = 0; ch < 4; ch++) {
            int i = ch * 64 + t;
            int v = (i < NDINV) ? bsums256[i] : 0;
            int incl = v;
            #pragma unroll
            for (int off = 1; off < 64; off <<= 1) {
                int u = __shfl_up(incl, off, 64);
                if (t >= off) incl += u;
            }
            bsN[i] = incl - v + carry;
            carry += __shfl(incl, 63, 64);
        }
    }
    __syncthreads();
    int node = blockIdx.x * 256 + t;
    if (node >= N_NODES) return;
    int base = rowoff[node] + bsN[node >> 8];
    int cnt  = deg[node];
    double acc0 = 0.0, acc1 = 0.0;
    int i = 0;
    for (; i + 2 <= cnt; i += 2) {
        int s0 = csr[base + i];
        int s1 = csr[base + i + 1];
        double2 p0 = ((const double2*)pack)[s0];   // {dinv, xw_s}
        double2 p1 = ((const double2*)pack)[s1];
        acc0 += p0.x * p0.y;
        acc1 += p1.x * p1.y;
    }
    if (i < cnt) {
        int s0 = csr[base + i];
        double2 p0 = ((const double2*)pack)[s0];
        acc0 += p0.x * p0.y;
    }
    score_sd[node] = pack[2 * node] * (acc0 + acc1);
}

// =============== K4: per-graph top-k (tanh finalize + bitonic, f64 keys) ===============

__global__ __launch_bounds__(512) void k4_topk(const double* __restrict__ score_sd,
                                               const double* __restrict__ pack,
                                               const double* __restrict__ sf,
                                               const float* __restrict__ bs,
                                               const int* __restrict__ batch,
                                               int* __restrict__ perm, int* __restrict__ nodemap,
                                               float* __restrict__ scoref_sel,
                                               float* __restrict__ out, long o2, long o3) {
    __shared__ double key[SORT_N];
    __shared__ int    idx[SORT_N];
    int g = blockIdx.x, t = threadIdx.x;
    const double A = 0.6, OMA = 1.0 - 0.6;
    double bsv = (double)bs[0];
    for (int i = t; i < SORT_N; i += 512) {
        if (i < NPGC) {
            int node = g * NPGC + i;
            double2 p = ((const double2*)pack)[node];   // {dinv, xw_s}
            double tot = score_sd[node] + p.x * p.x * p.y + bsv;  // + self loop + b_s
            key[i] = tanh(A * tot + OMA * sf[node]);
            idx[i] = i;
        } else { key[i] = -1e300; idx[i] = i; }
    }
    __syncthreads();
    for (int size = 2; size <= SORT_N; size <<= 1) {
        for (int stride = size >> 1; stride > 0; stride >>= 1) {
            int a = ((t & ~(stride - 1)) << 1) | (t & (stride - 1));
            int b = a | stride;
            bool descFirst = ((a & size) == 0);
            double ka = key[a], kb = key[b];
            int ia = idx[a], ib = idx[b];
            bool aAfterB = (ka < kb) || (ka == kb && ia > ib);  // stable descending
            if (descFirst ? aAfterB : !aAfterB) {
                key[a] = kb; key[b] = ka;
                idx[a] = ib; idx[b] = ia;
            }
            __syncthreads();
        }
    }
    for (int j = t; j < KSEL; j += 512) {
        int node = g * NPGC + idx[j];
        int pos  = g * KSEL + j;
        perm[pos]        = node;
        nodemap[node]    = pos + 1;             // 0 = unselected
        scoref_sel[pos]  = (float)key[j];
        out[o2 + pos]    = (float)batch[node];  // batch_out
        out[o3 + pos]    = (float)node;         // perm
    }
}

// =============== K5: edge flag+scan || fusion gather ===============

__global__ __launch_bounds__(256) void k5_escan_gather(const int* __restrict__ src,
                                                       const int* __restrict__ dst,
                                                       const int* __restrict__ nodemap,
                                                       int* __restrict__ epos,
                                                       int* __restrict__ bsumsE,
                                                       const float* __restrict__ xw,
                                                       const int* __restrict__ perm,
                                                       const int* __restrict__ rowoff,
                                                       const int* __restrict__ bsums256,
                                                       const int* __restrict__ deg,
                                                       const int* __restrict__ csr,
                                                       const float* __restrict__ dinvf,
                                                       const float* __restrict__ scoref_sel,
                                                       const float* __restrict__ b_fu,
                                                       float* __restrict__ out, long o4) {
    int t = threadIdx.x;
    int lane = t & 63, wid = t >> 6;
    if (blockIdx.x < NBE) {
        __shared__ int ws4[4];
        int base = blockIdx.x * 1024 + t * 4;
        int v0 = 0, v1 = 0, v2 = 0, v3 = 0;
        if (base + 0 < N_EDGES) v0 = (nodemap[src[base + 0]] > 0 && nodemap[dst[base + 0]] > 0);
        if (base + 1 < N_EDGES) v1 = (nodemap[src[base + 1]] > 0 && nodemap[dst[base + 1]] > 0);
        if (base + 2 < N_EDGES) v2 = (nodemap[src[base + 2]] > 0 && nodemap[dst[base + 2]] > 0);
        if (base + 3 < N_EDGES) v3 = (nodemap[src[base + 3]] > 0 && nodemap[dst[base + 3]] > 0);
        int s4 = v0 + v1 + v2 + v3;
        int incl = s4;
        #pragma unroll
        for (int off = 1; off < 64; off <<= 1) {
            int u = __shfl_up(incl, off, 64);
            if (lane >= off) incl += u;
        }
        if (lane == 63) ws4[wid] = incl;
        __syncthreads();
        int woff = 0;
        #pragma unroll
        for (int w = 0; w < 4; w++) if (w < wid) woff += ws4[w];
        int excl = incl - s4 + woff;
        if (base + 0 < N_EDGES) epos[base + 0] = excl;
        if (base + 1 < N_EDGES) epos[base + 1] = excl + v0;
        if (base + 2 < N_EDGES) epos[base + 2] = excl + v0 + v1;
        if (base + 3 < N_EDGES) epos[base + 3] = excl + v0 + v1 + v2;
        if (t == 255) bsumsE[blockIdx.x] = woff + incl;
        return;
    }
    __shared__ int bsN[256];
    if (t < 64) {
        int carry = 0;
        #pragma unroll
        for (int ch = 0; ch < 4; ch++) {
            int i = ch * 64 + t;
            int v = (i < NDINV) ? bsums256[i] : 0;
            int incl = v;
            #pragma unroll
            for (int off = 1; off < 64; off <<= 1) {
                int u = __shfl_up(incl, off, 64);
                if (t >= off) incl += u;
            }
            bsN[i] = incl - v + carry;
            carry += __shfl(incl, 63, 64);
        }
    }
    __syncthreads();
    int wave = (blockIdx.x - NBE) * 4 + wid;     // exactly 25000
    int p = perm[wave];
    float dpf = dinvf[p];
    int c2 = lane * 2;
    float2 v = ((const float2*)(xw + (size_t)p * DIM))[lane];
    float nself = dpf * dpf;
    float ax = nself * v.x, ay = nself * v.y;
    int beg = rowoff[p] + bsN[p >> 8], cnt = deg[p];
    int i = 0;
    for (; i + 2 <= cnt; i += 2) {
        int s0 = csr[beg + i];
        int s1 = csr[beg + i + 1];
        float2 u0 = ((const float2*)(xw + (size_t)s0 * DIM))[lane];
        float2 u1 = ((const float2*)(xw + (size_t)s1 * DIM))[lane];
        float n0 = dinvf[s0] * dpf, n1 = dinvf[s1] * dpf;
        ax += n0 * u0.x; ay += n0 * u0.y;
        ax += n1 * u1.x; ay += n1 * u1.y;
    }
    if (i < cnt) {
        int s0 = csr[beg + i];
        float2 u0 = ((const float2*)(xw + (size_t)s0 * DIM))[lane];
        float n0 = dinvf[s0] * dpf;
        ax += n0 * u0.x; ay += n0 * u0.y;
    }
    ax += b_fu[c2];
    ay += b_fu[c2 + 1];
    float sc = scoref_sel[wave];
    size_t ro = (size_t)wave * DIM + c2;
    out[o4 + ro]     = ax;        // x_ae
    out[o4 + ro + 1] = ay;
    out[ro]          = ax * sc;   // x_out
    out[ro + 1]      = ay * sc;
}

// =============== K6: edge compaction scatter (remap + write) ===============

__global__ __launch_bounds__(256) void k6_compact(const int* __restrict__ src,
                                                  const int* __restrict__ dst,
                                                  const int* __restrict__ nodemap,
                                                  const int* __restrict__ epos,
                                                  const int* __restrict__ bsumsE,
                                                  float* __restrict__ out_edges, long M) {
    __shared__ int bsE[512];
    int t = threadIdx.x;
    if (t < 64) {                               // wave 0: scan 489 entries, 8 chunks of 64
        int carry = 0;
        #pragma unroll
        for (int c = 0; c < 8; c++) {
            int i = c * 64 + t;
            int v = (i < NBE) ? bsumsE[i] : 0;
            int incl = v;
            #pragma unroll
            for (int off = 1; off < 64; off <<= 1) {
                int u = __shfl_up(incl, off, 64);
                if (t >= off) incl += u;
            }
            if (i < 512) bsE[i] = incl - v + carry;
            carry += __shfl(incl, 63, 64);
        }
    }
    __syncthreads();
    int e = blockIdx.x * 256 + t;
    if (e >= N_EDGES) return;
    int r = nodemap[src[e]], c = nodemap[dst[e]];
    if (r > 0 && c > 0) {
        int pos = epos[e] + bsE[e >> 10];
        out_edges[pos]     = (float)(r - 1);
        out_edges[M + pos] = (float)(c - 1);
    }
}

// ---------------- host ----------------

extern "C" void kernel_launch(void* const* d_in, const int* in_sizes, int n_in,
                              void* d_out, int out_size, void* d_ws, size_t ws_size,
                              hipStream_t stream) {
    const float* x    = (const float*)d_in[0];
    const int*   ei   = (const int*)d_in[1];
    const int*   src  = ei;
    const int*   dst  = ei + N_EDGES;
    const int*   batch= (const int*)d_in[2];
    const float* W_s  = (const float*)d_in[3];
    const float* b_s  = (const float*)d_in[4];
    const float* W_f  = (const float*)d_in[5];
    const float* b_f  = (const float*)d_in[6];
    const float* W_fu = (const float*)d_in[7];
    const float* b_fu = (const float*)d_in[8];
    float* out = (float*)d_out;

    char* wsp = (char*)d_ws;
    size_t off = 0;
    auto take = [&](size_t bytes) -> char* {
        char* p = wsp + off;
        off = (off + bytes + 255) & ~(size_t)255;
        return p;
    };
    // zero-cluster (single memset): degpriv | nodemap (0 = unselected)
    char*   zbase      = wsp;
    int*    degpriv    = (int*)   take((size_t)DEGB * N_NODES * 4);   // 12.8 MB
    int*    nodemap    = (int*)   take((size_t)N_NODES * 4);
    size_t  zbytes     = off;
    int*    eslot      = (int*)   take((size_t)N_EDGES * 4);
    int*    deg        = (int*)   take((size_t)N_NODES * 4);
    double* score_sd   = (double*)take((size_t)N_NODES * 8);
    double* pack       = (double*)take((size_t)N_NODES * 16);  // {dinv, xw_s} per node
    double* sf         = (double*)take((size_t)N_NODES * 8);
    float*  dinvf      = (float*) take((size_t)N_NODES * 4);
    float*  scoref_sel = (float*) take((size_t)NGRAPH * KSEL * 4);
    int*    perm       = (int*)   take((size_t)NGRAPH * KSEL * 4);
    int*    rowoff     = (int*)   take((size_t)N_NODES * 4);
    int*    epos       = (int*)   take((size_t)N_EDGES * 4);
    int*    bsumsE     = (int*)   take((size_t)1024 * 4);
    int*    bsums256   = (int*)   take((size_t)1024 * 4);
    int*    csr        = (int*)   take((size_t)N_EDGES * 4);
    float*  xw         = (float*) take((size_t)N_NODES * DIM * 4);

    // output layout: x_out[25000*128] | edge_index_new[2*M] | batch_out | perm | x_ae[25000*128]
    long M  = ((long)out_size - 6450000L) / 2;
    long o1 = 3200000L;
    long o2 = o1 + 2 * M;
    long o3 = o2 + (long)NGRAPH * KSEL;
    long o4 = o3 + (long)NGRAPH * KSEL;

    hipMemsetAsync(zbase, 0, zbytes, stream);

    k1_fused<<<DEGB + GEMM_BLKS, 256, 0, stream>>>(x, W_fu, xw, W_s, W_f, b_f, pack, sf,
                                                   dst, degpriv, eslot);
    k2_merge<<<NDINV, 256, 0, stream>>>(degpriv, deg, rowoff, bsums256, pack, dinvf);
    k3_csr<<<EDGE_BLKS, 256, 0, stream>>>(src, dst, rowoff, bsums256, degpriv, eslot, csr);
    k3b_score<<<NDINV, 256, 0, stream>>>(csr, rowoff, bsums256, deg, pack, score_sd);
    k4_topk<<<NGRAPH, 512, 0, stream>>>(score_sd, pack, sf, b_s, batch,
                                        perm, nodemap, scoref_sel, out, o2, o3);
    k5_escan_gather<<<NBE + GATH_BLKS, 256, 0, stream>>>(src, dst, nodemap, epos, bsumsE,
                                                         xw, perm, rowoff, bsums256, deg, csr,
                                                         dinvf, scoref_sel, b_fu, out, o4);
    k6_compact<<<EDGE_BLKS, 256, 0, stream>>>(src, dst, nodemap, epos, bsumsE, out + o1, M);
}